// Round 16
// baseline (331.265 us; speedup 1.0000x reference)
//
#include <hip/hip_runtime.h>
#include <hip/hip_bf16.h>

#define NN 50000
#define NE 800000
#define HD 128
#define G3 384   // 3*H
#define K2 256   // 2*H
#define NTILES 3125  // NN/16 exactly
#define S8 16        // slots per node per region
#define DENSE 64     // dense slots per node
#define BAND1 16672
#define BAND2 33344

typedef short s16x8 __attribute__((ext_vector_type(8)));
typedef float f32x4 __attribute__((ext_vector_type(4)));

static __device__ __forceinline__ ushort f2b(float f) {
    __hip_bfloat16 b = __float2bfloat16(f);
    return *(ushort*)&b;
}
static __device__ __forceinline__ float b2f(ushort u) {
    return __uint_as_float(((uint)u) << 16);
}
static __device__ __forceinline__ uint pk(ushort a, ushort b) {
    return (uint)a | ((uint)b << 16);
}
static __device__ __forceinline__ float fsig(float x) {
    return __builtin_amdgcn_rcpf(1.f + __builtin_amdgcn_exp2f(-x * 1.44269504f));
}
static __device__ __forceinline__ float ftanh(float x) {
    return 1.f - 2.f * __builtin_amdgcn_rcpf(1.f + __builtin_amdgcn_exp2f(x * 2.88539008f));
}

static __device__ __forceinline__ void gl_lds16(const void* g, void* l) {
    __builtin_amdgcn_global_load_lds(
        (const __attribute__((address_space(1))) uint*)(uintptr_t)g,
        (__attribute__((address_space(3))) uint*)(uintptr_t)l, 16, 0, 0);
}

// ---------------- one-pass CSR fill, XCD-split regions (fast scatter) ----------------
__global__ void k_fill1(const int* __restrict__ edges, int* __restrict__ cnt8,
                        ushort* __restrict__ slots8, uint* __restrict__ ovf,
                        int* __restrict__ ovfc) {
    int e = blockIdx.x * blockDim.x + threadIdx.x;
    if (e >= NE) return;
    int reg = blockIdx.x & 7;
    int s = edges[2 * e];
    int d = edges[2 * e + 1];
    int pos = atomicAdd(&cnt8[reg * NN + d], 1);
    if (pos < S8) {
        slots8[((size_t)reg * NN + d) * S8 + pos] = (ushort)s;
    } else {
        int o = atomicAdd(ovfc, 1);
        ovf[o] = ((uint)d << 16) | (uint)s;
    }
}

// ---------------- merge regions -> dense per-node list (fast gather layout) ----------
__global__ void k_merge(const int* __restrict__ cnt8, const ushort* __restrict__ slots8,
                        ushort* __restrict__ dense, int* __restrict__ deg_tot,
                        int* __restrict__ dcnt, uint* __restrict__ ovf,
                        int* __restrict__ ovfc) {
    int v = blockIdx.x * blockDim.x + threadIdx.x;
    if (v >= NN) return;
    int dg = 0, pos = 0;
    ushort* dst = dense + (size_t)v * DENSE;
#pragma unroll
    for (int r = 0; r < 8; r++) {
        int c = cnt8[r * NN + v];
        dg += c;
        int cc = c < S8 ? c : S8;
        const ushort* src = slots8 + ((size_t)r * NN + v) * S8;
        for (int j = 0; j < cc; j++) {
            ushort s = src[j];
            if (pos < DENSE) {
                dst[pos] = s;
            } else {
                int o = atomicAdd(ovfc, 1);
                ovf[o] = ((uint)v << 16) | (uint)s;
            }
            pos++;
        }
    }
    deg_tot[v] = dg;
    dcnt[v] = pos < DENSE ? pos : DENSE;
}

// ---------------- preprocessing kernel 0: B1 + c3 + h2b ----------------
__global__ void k_pre0(const float* __restrict__ W_ih, const float* __restrict__ W_msg,
                       const float* __restrict__ b_msg, const float* __restrict__ h,
                       float* __restrict__ B1, float* __restrict__ c3,
                       ushort* __restrict__ hb) {
    int b = blockIdx.x;
    int tid = threadIdx.x;
    if (b < 768) {
        int idx = b * 256 + tid;
        int k = idx % K2;
        int n = (idx / K2) % G3;
        int t = idx / (K2 * G3);
        const float* wi = W_ih + ((size_t)t * G3 + n) * K2;
        const float* wm = W_msg + (size_t)t * K2 * K2;
        float acc = 0.f;
#pragma unroll 8
        for (int j = 0; j < K2; j++) acc += wi[j] * wm[(size_t)j * K2 + k];
        B1[((size_t)t * K2 + k) * G3 + n] = acc;
    } else if (b < 771) {
        int idx = (b - 768) * 256 + tid;
        if (idx >= 2 * G3) return;
        int n = idx % G3;
        int t = idx / G3;
        const float* wi = W_ih + ((size_t)t * G3 + n) * K2;
        const float* bm = b_msg + t * K2;
        float acc = 0.f;
#pragma unroll 8
        for (int j = 0; j < K2; j++) acc += wi[j] * bm[j];
        c3[idx] = acc;
    } else {
        int i = (b - 771) * 256 + tid;
        if (i >= NN * HD / 4) return;
        float4 v = reinterpret_cast<const float4*>(h)[i];
        ushort4 o;
        o.x = f2b(v.x); o.y = f2b(v.y); o.z = f2b(v.z); o.w = f2b(v.w);
        reinterpret_cast<ushort4*>(hb)[i] = o;
    }
}

// ---------------- preprocessing kernel 1: pack B + biases ----------------
__global__ void k_pre1(const float* __restrict__ B1, const float* __restrict__ W_hh,
                       const float* __restrict__ b_ih, const float* __restrict__ b_hh,
                       const float* __restrict__ c3, ushort* __restrict__ Bq,
                       float* __restrict__ bih_p, float* __restrict__ bhh_p,
                       float* __restrict__ c3_p) {
    int b = blockIdx.x;
    int tid = threadIdx.x;
    if (b < 192) {
        int idx = b * 256 + tid;
        int lane = idx & 63;
        int slot = (idx >> 6) % 48;
        int slice = ((idx >> 6) / 48) % 8;
        int t = idx / (64 * 48 * 8);
        int slab = slot / 12;
        int rem = slot % 12;
        int kb = rem / 3, gate = rem % 3;
        int d = slice * 16 + (lane & 15);
        int kbase = kb * 32 + (lane >> 4) * 8;
        ushort* dst = Bq + (size_t)idx * 8;
#pragma unroll
        for (int e = 0; e < 8; e++) {
            int k = kbase + e;
            float v;
            if (slab == 0) {
                v = B1[((size_t)t * K2 + k) * G3 + gate * 128 + d];
            } else if (slab == 3) {
                v = W_hh[((size_t)t * G3 + gate * 128 + d) * HD + k];
            } else {
                float full = B1[((size_t)t * K2 + 128 + k) * G3 + gate * 128 + d];
                v = (slab == 1) ? full : (full - b2f(f2b(full)));
            }
            dst[e] = f2b(v);
        }
    } else {
        int idx = (b - 192) * 256 + tid;
        if (idx >= 2 * 8 * 3 * 16) return;
        int c = idx & 15;
        int g = (idx >> 4) % 3;
        int slice = ((idx >> 4) / 3) % 8;
        int t = idx / (16 * 3 * 8);
        int d = slice * 16 + c;
        bih_p[idx] = b_ih[t * G3 + g * 128 + d];
        bhh_p[idx] = b_hh[t * G3 + g * 128 + d];
        c3_p[idx]  = c3[t * G3 + g * 128 + d];
    }
}

// ---------------- prep: src-banded dense gather + write A frag order ----------------
// 3 passes over src bands of ~4.3MB of hb so each XCD's L2 holds the band.
// Out-of-band srcs contribute +0.0 (v=0 -> b2f(0)=0), so sums are exact reorders.
__global__ void k_prep(const ushort* __restrict__ hb, const float* __restrict__ hf,
                       const int* __restrict__ deg_tot, const int* __restrict__ dcnt,
                       const ushort* __restrict__ dense,
                       const uint* __restrict__ ovf, const int* __restrict__ ovfc,
                       ushort* __restrict__ FA) {
    int wv = (blockIdx.x * blockDim.x + threadIdx.x) >> 6;
    int lane = threadIdx.x & 63;
    if (wv >= NN) return;
    int dg = deg_tot[wv];
    int lim = dcnt[wv];
    const ushort* sl = dense + (size_t)wv * DENSE;
    float a0 = 0.f, a1 = 0.f;
#pragma unroll
    for (int pass = 0; pass < 3; pass++) {
        int lo = (pass == 0) ? 0 : ((pass == 1) ? BAND1 : BAND2);
        int hi = (pass == 0) ? BAND1 : ((pass == 1) ? BAND2 : 65536);
        int j = 0;
        for (; j + 4 <= lim; j += 4) {
            int s0 = sl[j], s1 = sl[j + 1], s2 = sl[j + 2], s3 = sl[j + 3];
            uint v0 = 0, v1 = 0, v2 = 0, v3 = 0;
            if (s0 >= lo && s0 < hi)
                v0 = *reinterpret_cast<const uint*>(hb + (size_t)s0 * HD + lane * 2);
            if (s1 >= lo && s1 < hi)
                v1 = *reinterpret_cast<const uint*>(hb + (size_t)s1 * HD + lane * 2);
            if (s2 >= lo && s2 < hi)
                v2 = *reinterpret_cast<const uint*>(hb + (size_t)s2 * HD + lane * 2);
            if (s3 >= lo && s3 < hi)
                v3 = *reinterpret_cast<const uint*>(hb + (size_t)s3 * HD + lane * 2);
            a0 += b2f((ushort)(v0 & 0xffff)) + b2f((ushort)(v1 & 0xffff)) +
                  b2f((ushort)(v2 & 0xffff)) + b2f((ushort)(v3 & 0xffff));
            a1 += b2f((ushort)(v0 >> 16)) + b2f((ushort)(v1 >> 16)) +
                  b2f((ushort)(v2 >> 16)) + b2f((ushort)(v3 >> 16));
        }
        for (; j < lim; j++) {
            int s = sl[j];
            if (s >= lo && s < hi) {
                uint v = *reinterpret_cast<const uint*>(hb + (size_t)s * HD + lane * 2);
                a0 += b2f((ushort)(v & 0xffff));
                a1 += b2f((ushort)(v >> 16));
            }
        }
    }
    if (dg > lim) {
        int oc = *ovfc;
        for (int k = 0; k < oc; k++) {
            uint pr = ovf[k];
            if ((int)(pr >> 16) == wv) {
                int s = (int)(pr & 0xffffu);
                uint v = *reinterpret_cast<const uint*>(hb + (size_t)s * HD + lane * 2);
                a0 += b2f((ushort)(v & 0xffff));
                a1 += b2f((ushort)(v >> 16));
            }
        }
    }
    int tile = wv >> 4, r = wv & 15;
    int kb = lane >> 4;
    int lp = r + (((lane & 15) >> 2) << 4);
    uint* base = reinterpret_cast<uint*>(FA) + (size_t)tile * 4096 + kb * 256 +
                 lp * 4 + (lane & 3);
    float2 hv = *reinterpret_cast<const float2*>(hf + (size_t)wv * HD + lane * 2);
    float dgf = (float)dg;
    float dh0 = dgf * hv.x, dh1 = dgf * hv.y;
    ushort p0 = f2b(dh0), p1 = f2b(dh1);
    ushort l0 = f2b(dh0 - b2f(p0)), l1 = f2b(dh1 - b2f(p1));
    base[0]    = pk(f2b(a0), f2b(a1));        // slab 0: s
    base[1024] = pk(p0, p1);                  // slab 1: dh_hi
    base[2048] = pk(l0, l1);                  // slab 2: dh_lo
    base[3072] = pk(f2b(hv.x), f2b(hv.y));    // slab 3: h_hi
}

// ---------------- fused MFMA GEMM + GRU: 8-wave octet blocks (round-14 proven) -------
#define BS(slab, kb, nf) \
    (*reinterpret_cast<const s16x8*>(&Bs[(size_t)((((slab) * 12 + (kb) * 3 + (nf)) * 64 + lane)) * 8]))

__global__ __launch_bounds__(512) void k_fused(
    const ushort* __restrict__ FA,      // [3125][16][64][8] bf16 frag-order A
    const ushort* __restrict__ Bq_t,    // [8][48][512] bf16 (this t)
    const float* __restrict__ bih_t,    // [8][3][16]
    const float* __restrict__ bhh_t,
    const float* __restrict__ c3_t,
    const int* __restrict__ deg,
    const float* __restrict__ hcur,     // [NN][128] f32
    float* __restrict__ hout,           // [NN][128] f32
    ushort* __restrict__ hb_out)        // [NN][128] bf16
{
    __shared__ __align__(16) ushort Bs[48 * 512];

    int tid = threadIdx.x;
    int bid = blockIdx.x;
    int r8 = bid & 7;
    int q = bid >> 3;
    int oct = (q >> 3) * 8 + r8;    // 0..103 ; valid < 98
    int slice = q & 7;
    if (oct * 32 >= NTILES) return; // whole block exits (uniform)
    int w = tid >> 6;               // 0..7
    int lane = tid & 63;
    int lhi = lane >> 4;
    int col = lane & 15;

    // stage B slice: 48 segs of 1KB; wave w loads 6
    const ushort* Bg = Bq_t + (size_t)slice * 48 * 512;
#pragma unroll
    for (int i = 0; i < 6; i++) {
        int seg = w * 6 + i;
        gl_lds16(Bg + (size_t)seg * 512 + lane * 8, &Bs[(size_t)seg * 512]);
    }

    int d = (slice << 4) + col;
    float bihv[3], bhhv[3], c3v[3];
#pragma unroll
    for (int g = 0; g < 3; g++) {
        int o = (slice * 3 + g) * 16 + col;
        bihv[g] = bih_t[o];
        bhhv[g] = bhh_t[o];
        c3v[g] = c3_t[o];
    }

    __syncthreads();   // single barrier: B resident (drains vmcnt)

#pragma unroll
    for (int it = 0; it < 4; it++) {
        int t = oct * 32 + w + 8 * it;   // wave-uniform
        if (t >= NTILES) break;
        const ushort* FAt = FA + (size_t)t * 8192;

        s16x8 As[4], Ahh[4], Ahl[4], Ah[4];
#pragma unroll
        for (int kb = 0; kb < 4; kb++) {
            As[kb]  = *reinterpret_cast<const s16x8*>(FAt + ((size_t)(kb) * 64 + lane) * 8);
            Ahh[kb] = *reinterpret_cast<const s16x8*>(FAt + ((size_t)(4 + kb) * 64 + lane) * 8);
            Ahl[kb] = *reinterpret_cast<const s16x8*>(FAt + ((size_t)(8 + kb) * 64 + lane) * 8);
            Ah[kb]  = *reinterpret_cast<const s16x8*>(FAt + ((size_t)(12 + kb) * 64 + lane) * 8);
        }

        int rbase0 = t * 16 + (lhi << 2);
        float hv[4];
        int dgi[4];
#pragma unroll
        for (int r = 0; r < 4; r++) {
            int m = rbase0 + r;
            int mm = m < NN ? m : 0;
            hv[r] = hcur[(size_t)mm * HD + d];
            dgi[r] = deg[mm];
        }

        f32x4 accI[3], accH[3];
#pragma unroll
        for (int i = 0; i < 3; i++) {
            accI[i] = f32x4{0.f, 0.f, 0.f, 0.f};
            accH[i] = f32x4{0.f, 0.f, 0.f, 0.f};
        }

#pragma unroll
        for (int kb = 0; kb < 4; kb++) {
#pragma unroll
            for (int nf = 0; nf < 3; nf++) {
                s16x8 b0 = BS(0, kb, nf);
                accI[nf] = __builtin_amdgcn_mfma_f32_16x16x32_bf16(As[kb], b0, accI[nf], 0, 0, 0);
                s16x8 b1 = BS(1, kb, nf);
                accI[nf] = __builtin_amdgcn_mfma_f32_16x16x32_bf16(Ahh[kb], b1, accI[nf], 0, 0, 0);
                accI[nf] = __builtin_amdgcn_mfma_f32_16x16x32_bf16(Ahl[kb], b1, accI[nf], 0, 0, 0);
                s16x8 b2 = BS(2, kb, nf);
                accI[nf] = __builtin_amdgcn_mfma_f32_16x16x32_bf16(Ahh[kb], b2, accI[nf], 0, 0, 0);
                s16x8 b3 = BS(3, kb, nf);
                accH[nf] = __builtin_amdgcn_mfma_f32_16x16x32_bf16(Ah[kb], b3, accH[nf], 0, 0, 0);
            }
        }

#pragma unroll
        for (int r = 0; r < 4; r++) {
            int m = rbase0 + r;
            bool wr = m < NN;
            float dgf = (float)dgi[r];
            float ir  = accI[0][r] + dgf * c3v[0] + bihv[0];
            float iz  = accI[1][r] + dgf * c3v[1] + bihv[1];
            float in_ = accI[2][r] + dgf * c3v[2] + bihv[2];
            float hr = accH[0][r] + bhhv[0];
            float hz = accH[1][r] + bhhv[1];
            float hn = accH[2][r] + bhhv[2];
            float rg = fsig(ir + hr);
            float zg = fsig(iz + hz);
            float ng = ftanh(in_ + rg * hn);
            float hnew = (1.f - zg) * ng + zg * hv[r];
            float res = (dgi[r] > 0) ? hnew : hv[r];
            if (wr) {
                hout[(size_t)m * HD + d] = res;
                hb_out[(size_t)m * HD + d] = f2b(res);
            }
        }
    }
}

extern "C" void kernel_launch(void* const* d_in, const int* in_sizes, int n_in,
                              void* d_out, int out_size, void* d_ws, size_t ws_size,
                              hipStream_t stream) {
    const float* h_in  = (const float*)d_in[0];
    const int*   edges = (const int*)d_in[1];
    const float* W_msg = (const float*)d_in[2];
    const float* b_msg = (const float*)d_in[3];
    const float* W_ih  = (const float*)d_in[4];
    const float* W_hh  = (const float*)d_in[5];
    const float* b_ih  = (const float*)d_in[6];
    const float* b_hh  = (const float*)d_in[7];
    float* out = (float*)d_out;

    char* p = (char*)d_ws;
    auto alloc = [&](size_t bytes) {
        void* r = (void*)p;
        p += (bytes + 255) / 256 * 256;
        return r;
    };
    int*    cnt8    = (int*)alloc((size_t)(8 * NN + 1) * 4);  // +1: ovf counter
    ushort* slots8  = (ushort*)alloc((size_t)8 * NN * S8 * 2);
    ushort* dense   = (ushort*)alloc((size_t)NN * DENSE * 2);
    uint*   ovf     = (uint*)alloc((size_t)NE * 4);
    int*    deg_tot = (int*)alloc((size_t)NN * 4);
    int*    dcnt    = (int*)alloc((size_t)NN * 4);
    float*  B1      = (float*)alloc((size_t)2 * K2 * G3 * 4);
    float*  c3      = (float*)alloc((size_t)2 * G3 * 4);
    ushort* Bq      = (ushort*)alloc((size_t)2 * 8 * 48 * 512 * 2);
    float*  bih_p   = (float*)alloc((size_t)2 * 8 * 3 * 16 * 4);
    float*  bhh_p   = (float*)alloc((size_t)2 * 8 * 3 * 16 * 4);
    float*  c3_p    = (float*)alloc((size_t)2 * 8 * 3 * 16 * 4);
    ushort* hb0     = (ushort*)alloc((size_t)NN * HD * 2);
    ushort* hb1     = (ushort*)alloc((size_t)NN * HD * 2);
    ushort* FA      = (ushort*)alloc((size_t)NTILES * 8192 * 2);
    float*  h1      = (float*)alloc((size_t)NN * HD * 4);
    int*    ovfc    = cnt8 + 8 * NN;

    hipMemsetAsync(cnt8, 0, (size_t)(8 * NN + 1) * 4, stream);
    k_fill1<<<(NE + 255) / 256, 256, 0, stream>>>(edges, cnt8, slots8, ovf, ovfc);
    k_merge<<<(NN + 255) / 256, 256, 0, stream>>>(cnt8, slots8, dense, deg_tot, dcnt,
                                                  ovf, ovfc);
    k_pre0<<<771 + (NN * HD / 4 + 255) / 256, 256, 0, stream>>>(
        W_ih, W_msg, b_msg, h_in, B1, c3, hb0);
    k_pre1<<<195, 256, 0, stream>>>(B1, W_hh, b_ih, b_hh, c3, Bq, bih_p, bhh_p, c3_p);

    const int FGRID = 832;
    const size_t BqT = (size_t)8 * 48 * 512;   // ushort units per t
    const size_t biasT = (size_t)8 * 3 * 16;

    // step 0
    k_prep<<<(NN * 64 + 255) / 256, 256, 0, stream>>>(hb0, h_in, deg_tot, dcnt, dense,
                                                      ovf, ovfc, FA);
    k_fused<<<FGRID, 512, 0, stream>>>(FA, Bq, bih_p, bhh_p, c3_p, deg_tot, h_in, h1, hb1);
    // step 1 (hb0 is rebuilt by k_pre0 every launch)
    k_prep<<<(NN * 64 + 255) / 256, 256, 0, stream>>>(hb1, h1, deg_tot, dcnt, dense,
                                                      ovf, ovfc, FA);
    k_fused<<<FGRID, 512, 0, stream>>>(FA, Bq + BqT, bih_p + biasT, bhh_p + biasT,
                                       c3_p + biasT, deg_tot, h1, out, hb0);
}

// Round 17
// 300.654 us; speedup vs baseline: 1.1018x; 1.1018x over previous
//
#include <hip/hip_runtime.h>
#include <hip/hip_bf16.h>

#define NN 50000
#define NE 800000
#define HD 128
#define G3 384   // 3*H
#define K2 256   // 2*H
#define NTILES 3125  // NN/16 exactly
#define S8 16        // slots per node per region
#define DENSE 64     // dense slots per node

typedef short s16x8 __attribute__((ext_vector_type(8)));
typedef float f32x4 __attribute__((ext_vector_type(4)));

static __device__ __forceinline__ ushort f2b(float f) {
    __hip_bfloat16 b = __float2bfloat16(f);
    return *(ushort*)&b;
}
static __device__ __forceinline__ float b2f(ushort u) {
    return __uint_as_float(((uint)u) << 16);
}
static __device__ __forceinline__ uint pk(ushort a, ushort b) {
    return (uint)a | ((uint)b << 16);
}
static __device__ __forceinline__ float fsig(float x) {
    return __builtin_amdgcn_rcpf(1.f + __builtin_amdgcn_exp2f(-x * 1.44269504f));
}
static __device__ __forceinline__ float ftanh(float x) {
    return 1.f - 2.f * __builtin_amdgcn_rcpf(1.f + __builtin_amdgcn_exp2f(x * 2.88539008f));
}

static __device__ __forceinline__ void gl_lds16(const void* g, void* l) {
    __builtin_amdgcn_global_load_lds(
        (const __attribute__((address_space(1))) uint*)(uintptr_t)g,
        (__attribute__((address_space(3))) uint*)(uintptr_t)l, 16, 0, 0);
}

// ---------------- one-pass CSR fill, XCD-split regions (fast scatter) ----------------
__global__ void k_fill1(const int* __restrict__ edges, int* __restrict__ cnt8,
                        ushort* __restrict__ slots8, uint* __restrict__ ovf,
                        int* __restrict__ ovfc) {
    int e = blockIdx.x * blockDim.x + threadIdx.x;
    if (e >= NE) return;
    int reg = blockIdx.x & 7;
    int s = edges[2 * e];
    int d = edges[2 * e + 1];
    int pos = atomicAdd(&cnt8[reg * NN + d], 1);
    if (pos < S8) {
        slots8[((size_t)reg * NN + d) * S8 + pos] = (ushort)s;
    } else {
        int o = atomicAdd(ovfc, 1);
        ovf[o] = ((uint)d << 16) | (uint)s;
    }
}

// ---------------- merge regions -> dense per-node list (fast gather layout) ----------
__global__ void k_merge(const int* __restrict__ cnt8, const ushort* __restrict__ slots8,
                        ushort* __restrict__ dense, int* __restrict__ deg_tot,
                        int* __restrict__ dcnt, uint* __restrict__ ovf,
                        int* __restrict__ ovfc) {
    int v = blockIdx.x * blockDim.x + threadIdx.x;
    if (v >= NN) return;
    int dg = 0, pos = 0;
    ushort* dst = dense + (size_t)v * DENSE;
#pragma unroll
    for (int r = 0; r < 8; r++) {
        int c = cnt8[r * NN + v];
        dg += c;
        int cc = c < S8 ? c : S8;
        const ushort* src = slots8 + ((size_t)r * NN + v) * S8;
        for (int j = 0; j < cc; j++) {
            ushort s = src[j];
            if (pos < DENSE) {
                dst[pos] = s;
            } else {
                int o = atomicAdd(ovfc, 1);
                ovf[o] = ((uint)v << 16) | (uint)s;
            }
            pos++;
        }
    }
    deg_tot[v] = dg;
    dcnt[v] = pos < DENSE ? pos : DENSE;
}

// ---------------- preprocessing kernel 0: B1 + c3 + h2b ----------------
__global__ void k_pre0(const float* __restrict__ W_ih, const float* __restrict__ W_msg,
                       const float* __restrict__ b_msg, const float* __restrict__ h,
                       float* __restrict__ B1, float* __restrict__ c3,
                       ushort* __restrict__ hb) {
    int b = blockIdx.x;
    int tid = threadIdx.x;
    if (b < 768) {
        int idx = b * 256 + tid;
        int k = idx % K2;
        int n = (idx / K2) % G3;
        int t = idx / (K2 * G3);
        const float* wi = W_ih + ((size_t)t * G3 + n) * K2;
        const float* wm = W_msg + (size_t)t * K2 * K2;
        float acc = 0.f;
#pragma unroll 8
        for (int j = 0; j < K2; j++) acc += wi[j] * wm[(size_t)j * K2 + k];
        B1[((size_t)t * K2 + k) * G3 + n] = acc;
    } else if (b < 771) {
        int idx = (b - 768) * 256 + tid;
        if (idx >= 2 * G3) return;
        int n = idx % G3;
        int t = idx / G3;
        const float* wi = W_ih + ((size_t)t * G3 + n) * K2;
        const float* bm = b_msg + t * K2;
        float acc = 0.f;
#pragma unroll 8
        for (int j = 0; j < K2; j++) acc += wi[j] * bm[j];
        c3[idx] = acc;
    } else {
        int i = (b - 771) * 256 + tid;
        if (i >= NN * HD / 4) return;
        float4 v = reinterpret_cast<const float4*>(h)[i];
        ushort4 o;
        o.x = f2b(v.x); o.y = f2b(v.y); o.z = f2b(v.z); o.w = f2b(v.w);
        reinterpret_cast<ushort4*>(hb)[i] = o;
    }
}

// ---------------- preprocessing kernel 1: pack B + biases ----------------
__global__ void k_pre1(const float* __restrict__ B1, const float* __restrict__ W_hh,
                       const float* __restrict__ b_ih, const float* __restrict__ b_hh,
                       const float* __restrict__ c3, ushort* __restrict__ Bq,
                       float* __restrict__ bih_p, float* __restrict__ bhh_p,
                       float* __restrict__ c3_p) {
    int b = blockIdx.x;
    int tid = threadIdx.x;
    if (b < 192) {
        int idx = b * 256 + tid;
        int lane = idx & 63;
        int slot = (idx >> 6) % 48;
        int slice = ((idx >> 6) / 48) % 8;
        int t = idx / (64 * 48 * 8);
        int slab = slot / 12;
        int rem = slot % 12;
        int kb = rem / 3, gate = rem % 3;
        int d = slice * 16 + (lane & 15);
        int kbase = kb * 32 + (lane >> 4) * 8;
        ushort* dst = Bq + (size_t)idx * 8;
#pragma unroll
        for (int e = 0; e < 8; e++) {
            int k = kbase + e;
            float v;
            if (slab == 0) {
                v = B1[((size_t)t * K2 + k) * G3 + gate * 128 + d];
            } else if (slab == 3) {
                v = W_hh[((size_t)t * G3 + gate * 128 + d) * HD + k];
            } else {
                float full = B1[((size_t)t * K2 + 128 + k) * G3 + gate * 128 + d];
                v = (slab == 1) ? full : (full - b2f(f2b(full)));
            }
            dst[e] = f2b(v);
        }
    } else {
        int idx = (b - 192) * 256 + tid;
        if (idx >= 2 * 8 * 3 * 16) return;
        int c = idx & 15;
        int g = (idx >> 4) % 3;
        int slice = ((idx >> 4) / 3) % 8;
        int t = idx / (16 * 3 * 8);
        int d = slice * 16 + c;
        bih_p[idx] = b_ih[t * G3 + g * 128 + d];
        bhh_p[idx] = b_hh[t * G3 + g * 128 + d];
        c3_p[idx]  = c3[t * G3 + g * 128 + d];
    }
}

// ---------------- prep: dense gather + write A [s|dh_hi|dh_lo|h_hi] frag order ------
// (round-14 exact form)
__global__ void k_prep(const ushort* __restrict__ hb, const float* __restrict__ hf,
                       const int* __restrict__ deg_tot, const int* __restrict__ dcnt,
                       const ushort* __restrict__ dense,
                       const uint* __restrict__ ovf, const int* __restrict__ ovfc,
                       ushort* __restrict__ FA) {
    int wv = (blockIdx.x * blockDim.x + threadIdx.x) >> 6;
    int lane = threadIdx.x & 63;
    if (wv >= NN) return;
    int dg = deg_tot[wv];
    int lim = dcnt[wv];
    const ushort* sl = dense + (size_t)wv * DENSE;
    float a0 = 0.f, a1 = 0.f;
    int j = 0;
    for (; j + 16 <= lim; j += 16) {
        uint v[16];
#pragma unroll
        for (int q = 0; q < 16; q++) {
            int s = sl[j + q];
            v[q] = *reinterpret_cast<const uint*>(hb + (size_t)s * HD + lane * 2);
        }
#pragma unroll
        for (int q = 0; q < 16; q++) {
            a0 += b2f((ushort)(v[q] & 0xffff));
            a1 += b2f((ushort)(v[q] >> 16));
        }
    }
    for (; j + 4 <= lim; j += 4) {
        uint v[4];
#pragma unroll
        for (int q = 0; q < 4; q++) {
            int s = sl[j + q];
            v[q] = *reinterpret_cast<const uint*>(hb + (size_t)s * HD + lane * 2);
        }
#pragma unroll
        for (int q = 0; q < 4; q++) {
            a0 += b2f((ushort)(v[q] & 0xffff));
            a1 += b2f((ushort)(v[q] >> 16));
        }
    }
    for (; j < lim; j++) {
        int s = sl[j];
        uint v = *reinterpret_cast<const uint*>(hb + (size_t)s * HD + lane * 2);
        a0 += b2f((ushort)(v & 0xffff));
        a1 += b2f((ushort)(v >> 16));
    }
    if (dg > lim) {
        int oc = *ovfc;
        for (int k = 0; k < oc; k++) {
            uint pr = ovf[k];
            if ((int)(pr >> 16) == wv) {
                int s = (int)(pr & 0xffffu);
                uint v = *reinterpret_cast<const uint*>(hb + (size_t)s * HD + lane * 2);
                a0 += b2f((ushort)(v & 0xffff));
                a1 += b2f((ushort)(v >> 16));
            }
        }
    }
    int tile = wv >> 4, r = wv & 15;
    int kb = lane >> 4;
    int lp = r + (((lane & 15) >> 2) << 4);
    uint* base = reinterpret_cast<uint*>(FA) + (size_t)tile * 4096 + kb * 256 +
                 lp * 4 + (lane & 3);
    float2 hv = *reinterpret_cast<const float2*>(hf + (size_t)wv * HD + lane * 2);
    float dgf = (float)dg;
    float dh0 = dgf * hv.x, dh1 = dgf * hv.y;
    ushort p0 = f2b(dh0), p1 = f2b(dh1);
    ushort l0 = f2b(dh0 - b2f(p0)), l1 = f2b(dh1 - b2f(p1));
    base[0]    = pk(f2b(a0), f2b(a1));        // slab 0: s
    base[1024] = pk(p0, p1);                  // slab 1: dh_hi
    base[2048] = pk(l0, l1);                  // slab 2: dh_lo
    base[3072] = pk(f2b(hv.x), f2b(hv.y));    // slab 3: h_hi
}

// ---------------- fused MFMA GEMM + GRU: 8-wave octet blocks, PAIR-TILE B-reuse ------
// 832 blocks x 512 thr; block = (oct: 32 tiles, slice); 8 waves x 2 pair-iterations.
// Each B fragment ds_read feeds BOTH tiles of a pair (24 reads/tile vs 48).
#define BS(slab, kb, nf) \
    (*reinterpret_cast<const s16x8*>(&Bs[(size_t)((((slab) * 12 + (kb) * 3 + (nf)) * 64 + lane)) * 8]))

__global__ __launch_bounds__(512) void k_fused(
    const ushort* __restrict__ FA,      // [3125][16][64][8] bf16 frag-order A
    const ushort* __restrict__ Bq_t,    // [8][48][512] bf16 (this t)
    const float* __restrict__ bih_t,    // [8][3][16]
    const float* __restrict__ bhh_t,
    const float* __restrict__ c3_t,
    const int* __restrict__ deg,
    const float* __restrict__ hcur,     // [NN][128] f32
    float* __restrict__ hout,           // [NN][128] f32
    ushort* __restrict__ hb_out)        // [NN][128] bf16
{
    __shared__ __align__(16) ushort Bs[48 * 512];

    int tid = threadIdx.x;
    int bid = blockIdx.x;
    int r8 = bid & 7;
    int q = bid >> 3;
    int oct = (q >> 3) * 8 + r8;    // 0..103 ; valid < 98
    int slice = q & 7;
    if (oct * 32 >= NTILES) return; // whole block exits (uniform)
    int w = tid >> 6;               // 0..7
    int lane = tid & 63;
    int lhi = lane >> 4;
    int col = lane & 15;

    // stage B slice: 48 segs of 1KB; wave w loads 6
    const ushort* Bg = Bq_t + (size_t)slice * 48 * 512;
#pragma unroll
    for (int i = 0; i < 6; i++) {
        int seg = w * 6 + i;
        gl_lds16(Bg + (size_t)seg * 512 + lane * 8, &Bs[(size_t)seg * 512]);
    }

    int d = (slice << 4) + col;
    float bihv[3], bhhv[3], c3v[3];
#pragma unroll
    for (int g = 0; g < 3; g++) {
        int o = (slice * 3 + g) * 16 + col;
        bihv[g] = bih_t[o];
        bhhv[g] = bhh_t[o];
        c3v[g] = c3_t[o];
    }

    __syncthreads();   // single barrier: B resident (drains vmcnt)

#pragma unroll
    for (int it = 0; it < 2; it++) {
        int t0 = oct * 32 + w * 2 + it * 16;   // wave-uniform pair (t0, t0+1)
        if (t0 >= NTILES) break;
        int t1 = t0 + 1;
        int tc1 = t1 < NTILES ? t1 : NTILES - 1;
        const ushort* FA0 = FA + (size_t)t0 * 8192;
        const ushort* FA1 = FA + (size_t)tc1 * 8192;

        // A-frags for both tiles (issued together: 32 x 1KB coalesced loads)
        s16x8 A0s[4], A0hh[4], A0hl[4], A0h[4];
        s16x8 A1s[4], A1hh[4], A1hl[4], A1h[4];
#pragma unroll
        for (int kb = 0; kb < 4; kb++) {
            A0s[kb]  = *reinterpret_cast<const s16x8*>(FA0 + ((size_t)(kb) * 64 + lane) * 8);
            A0hh[kb] = *reinterpret_cast<const s16x8*>(FA0 + ((size_t)(4 + kb) * 64 + lane) * 8);
            A0hl[kb] = *reinterpret_cast<const s16x8*>(FA0 + ((size_t)(8 + kb) * 64 + lane) * 8);
            A0h[kb]  = *reinterpret_cast<const s16x8*>(FA0 + ((size_t)(12 + kb) * 64 + lane) * 8);
            A1s[kb]  = *reinterpret_cast<const s16x8*>(FA1 + ((size_t)(kb) * 64 + lane) * 8);
            A1hh[kb] = *reinterpret_cast<const s16x8*>(FA1 + ((size_t)(4 + kb) * 64 + lane) * 8);
            A1hl[kb] = *reinterpret_cast<const s16x8*>(FA1 + ((size_t)(8 + kb) * 64 + lane) * 8);
            A1h[kb]  = *reinterpret_cast<const s16x8*>(FA1 + ((size_t)(12 + kb) * 64 + lane) * 8);
        }

        int rb0 = t0 * 16 + (lhi << 2);
        int rb1 = t1 * 16 + (lhi << 2);
        float hv0[4], hv1[4];
        int dg0[4], dg1[4];
#pragma unroll
        for (int r = 0; r < 4; r++) {
            int m0 = rb0 + r;
            int m1 = rb1 + r;
            int mm1 = m1 < NN ? m1 : 0;
            hv0[r] = hcur[(size_t)m0 * HD + d];
            dg0[r] = deg[m0];
            hv1[r] = hcur[(size_t)mm1 * HD + d];
            dg1[r] = deg[mm1];
        }

        f32x4 aI0[3], aH0[3], aI1[3], aH1[3];
#pragma unroll
        for (int i = 0; i < 3; i++) {
            aI0[i] = f32x4{0.f, 0.f, 0.f, 0.f};
            aH0[i] = f32x4{0.f, 0.f, 0.f, 0.f};
            aI1[i] = f32x4{0.f, 0.f, 0.f, 0.f};
            aH1[i] = f32x4{0.f, 0.f, 0.f, 0.f};
        }

#pragma unroll
        for (int kb = 0; kb < 4; kb++) {
#pragma unroll
            for (int nf = 0; nf < 3; nf++) {
                s16x8 b0 = BS(0, kb, nf);
                aI0[nf] = __builtin_amdgcn_mfma_f32_16x16x32_bf16(A0s[kb], b0, aI0[nf], 0, 0, 0);
                aI1[nf] = __builtin_amdgcn_mfma_f32_16x16x32_bf16(A1s[kb], b0, aI1[nf], 0, 0, 0);
                s16x8 b1 = BS(1, kb, nf);
                aI0[nf] = __builtin_amdgcn_mfma_f32_16x16x32_bf16(A0hh[kb], b1, aI0[nf], 0, 0, 0);
                aI0[nf] = __builtin_amdgcn_mfma_f32_16x16x32_bf16(A0hl[kb], b1, aI0[nf], 0, 0, 0);
                aI1[nf] = __builtin_amdgcn_mfma_f32_16x16x32_bf16(A1hh[kb], b1, aI1[nf], 0, 0, 0);
                aI1[nf] = __builtin_amdgcn_mfma_f32_16x16x32_bf16(A1hl[kb], b1, aI1[nf], 0, 0, 0);
                s16x8 b2 = BS(2, kb, nf);
                aI0[nf] = __builtin_amdgcn_mfma_f32_16x16x32_bf16(A0hh[kb], b2, aI0[nf], 0, 0, 0);
                aI1[nf] = __builtin_amdgcn_mfma_f32_16x16x32_bf16(A1hh[kb], b2, aI1[nf], 0, 0, 0);
                s16x8 b3 = BS(3, kb, nf);
                aH0[nf] = __builtin_amdgcn_mfma_f32_16x16x32_bf16(A0h[kb], b3, aH0[nf], 0, 0, 0);
                aH1[nf] = __builtin_amdgcn_mfma_f32_16x16x32_bf16(A1h[kb], b3, aH1[nf], 0, 0, 0);
            }
        }

#pragma unroll
        for (int r = 0; r < 4; r++) {
            int m = rb0 + r;
            float dgf = (float)dg0[r];
            float ir  = aI0[0][r] + dgf * c3v[0] + bihv[0];
            float iz  = aI0[1][r] + dgf * c3v[1] + bihv[1];
            float in_ = aI0[2][r] + dgf * c3v[2] + bihv[2];
            float hr = aH0[0][r] + bhhv[0];
            float hz = aH0[1][r] + bhhv[1];
            float hn = aH0[2][r] + bhhv[2];
            float rg = fsig(ir + hr);
            float zg = fsig(iz + hz);
            float ng = ftanh(in_ + rg * hn);
            float hnew = (1.f - zg) * ng + zg * hv0[r];
            float res = (dg0[r] > 0) ? hnew : hv0[r];
            hout[(size_t)m * HD + d] = res;
            hb_out[(size_t)m * HD + d] = f2b(res);
        }
#pragma unroll
        for (int r = 0; r < 4; r++) {
            int m = rb1 + r;
            if (m >= NN) continue;
            float dgf = (float)dg1[r];
            float ir  = aI1[0][r] + dgf * c3v[0] + bihv[0];
            float iz  = aI1[1][r] + dgf * c3v[1] + bihv[1];
            float in_ = aI1[2][r] + dgf * c3v[2] + bihv[2];
            float hr = aH1[0][r] + bhhv[0];
            float hz = aH1[1][r] + bhhv[1];
            float hn = aH1[2][r] + bhhv[2];
            float rg = fsig(ir + hr);
            float zg = fsig(iz + hz);
            float ng = ftanh(in_ + rg * hn);
            float hnew = (1.f - zg) * ng + zg * hv1[r];
            float res = (dg1[r] > 0) ? hnew : hv1[r];
            hout[(size_t)m * HD + d] = res;
            hb_out[(size_t)m * HD + d] = f2b(res);
        }
    }
}

extern "C" void kernel_launch(void* const* d_in, const int* in_sizes, int n_in,
                              void* d_out, int out_size, void* d_ws, size_t ws_size,
                              hipStream_t stream) {
    const float* h_in  = (const float*)d_in[0];
    const int*   edges = (const int*)d_in[1];
    const float* W_msg = (const float*)d_in[2];
    const float* b_msg = (const float*)d_in[3];
    const float* W_ih  = (const float*)d_in[4];
    const float* W_hh  = (const float*)d_in[5];
    const float* b_ih  = (const float*)d_in[6];
    const float* b_hh  = (const float*)d_in[7];
    float* out = (float*)d_out;

    char* p = (char*)d_ws;
    auto alloc = [&](size_t bytes) {
        void* r = (void*)p;
        p += (bytes + 255) / 256 * 256;
        return r;
    };
    int*    cnt8    = (int*)alloc((size_t)(8 * NN + 1) * 4);  // +1: ovf counter
    ushort* slots8  = (ushort*)alloc((size_t)8 * NN * S8 * 2);
    ushort* dense   = (ushort*)alloc((size_t)NN * DENSE * 2);
    uint*   ovf     = (uint*)alloc((size_t)NE * 4);
    int*    deg_tot = (int*)alloc((size_t)NN * 4);
    int*    dcnt    = (int*)alloc((size_t)NN * 4);
    float*  B1      = (float*)alloc((size_t)2 * K2 * G3 * 4);
    float*  c3      = (float*)alloc((size_t)2 * G3 * 4);
    ushort* Bq      = (ushort*)alloc((size_t)2 * 8 * 48 * 512 * 2);
    float*  bih_p   = (float*)alloc((size_t)2 * 8 * 3 * 16 * 4);
    float*  bhh_p   = (float*)alloc((size_t)2 * 8 * 3 * 16 * 4);
    float*  c3_p    = (float*)alloc((size_t)2 * 8 * 3 * 16 * 4);
    ushort* hb0     = (ushort*)alloc((size_t)NN * HD * 2);
    ushort* hb1     = (ushort*)alloc((size_t)NN * HD * 2);
    ushort* FA      = (ushort*)alloc((size_t)NTILES * 8192 * 2);
    float*  h1      = (float*)alloc((size_t)NN * HD * 4);
    int*    ovfc    = cnt8 + 8 * NN;

    hipMemsetAsync(cnt8, 0, (size_t)(8 * NN + 1) * 4, stream);
    k_fill1<<<(NE + 255) / 256, 256, 0, stream>>>(edges, cnt8, slots8, ovf, ovfc);
    k_merge<<<(NN + 255) / 256, 256, 0, stream>>>(cnt8, slots8, dense, deg_tot, dcnt,
                                                  ovf, ovfc);
    k_pre0<<<771 + (NN * HD / 4 + 255) / 256, 256, 0, stream>>>(
        W_ih, W_msg, b_msg, h_in, B1, c3, hb0);
    k_pre1<<<195, 256, 0, stream>>>(B1, W_hh, b_ih, b_hh, c3, Bq, bih_p, bhh_p, c3_p);

    const int FGRID = 832;
    const size_t BqT = (size_t)8 * 48 * 512;   // ushort units per t
    const size_t biasT = (size_t)8 * 3 * 16;

    // step 0
    k_prep<<<(NN * 64 + 255) / 256, 256, 0, stream>>>(hb0, h_in, deg_tot, dcnt, dense,
                                                      ovf, ovfc, FA);
    k_fused<<<FGRID, 512, 0, stream>>>(FA, Bq, bih_p, bhh_p, c3_p, deg_tot, h_in, h1, hb1);
    // step 1 (hb0 is rebuilt by k_pre0 every launch)
    k_prep<<<(NN * 64 + 255) / 256, 256, 0, stream>>>(hb1, h1, deg_tot, dcnt, dense,
                                                      ovf, ovfc, FA);
    k_fused<<<FGRID, 512, 0, stream>>>(FA, Bq + BqT, bih_p + biasT, bhh_p + biasT,
                                       c3_p + biasT, deg_tot, h1, out, hb0);
}

// Round 18
// 259.626 us; speedup vs baseline: 1.2759x; 1.1580x over previous
//
#include <hip/hip_runtime.h>
#include <hip/hip_bf16.h>

#define NN 50000
#define NE 800000
#define HD 128
#define G3 384   // 3*H
#define K2 256   // 2*H
#define NTILES 3125  // NN/16 exactly
#define S8 16        // slots per node per region
#define DENSE 64     // dense slots per node

typedef short s16x8 __attribute__((ext_vector_type(8)));
typedef float f32x4 __attribute__((ext_vector_type(4)));

static __device__ __forceinline__ ushort f2b(float f) {
    __hip_bfloat16 b = __float2bfloat16(f);
    return *(ushort*)&b;
}
static __device__ __forceinline__ float b2f(ushort u) {
    return __uint_as_float(((uint)u) << 16);
}
static __device__ __forceinline__ uint pk(ushort a, ushort b) {
    return (uint)a | ((uint)b << 16);
}
static __device__ __forceinline__ float fsig(float x) {
    return __builtin_amdgcn_rcpf(1.f + __builtin_amdgcn_exp2f(-x * 1.44269504f));
}
static __device__ __forceinline__ float ftanh(float x) {
    return 1.f - 2.f * __builtin_amdgcn_rcpf(1.f + __builtin_amdgcn_exp2f(x * 2.88539008f));
}

static __device__ __forceinline__ void gl_lds16(const void* g, void* l) {
    __builtin_amdgcn_global_load_lds(
        (const __attribute__((address_space(1))) uint*)(uintptr_t)g,
        (__attribute__((address_space(3))) uint*)(uintptr_t)l, 16, 0, 0);
}

// ---------------- one-pass CSR fill, XCD-split regions (fast scatter) ----------------
__global__ void k_fill1(const int* __restrict__ edges, int* __restrict__ cnt8,
                        ushort* __restrict__ slots8, uint* __restrict__ ovf,
                        int* __restrict__ ovfc) {
    int e = blockIdx.x * blockDim.x + threadIdx.x;
    if (e >= NE) return;
    int reg = blockIdx.x & 7;
    int s = edges[2 * e];
    int d = edges[2 * e + 1];
    int pos = atomicAdd(&cnt8[reg * NN + d], 1);
    if (pos < S8) {
        slots8[((size_t)reg * NN + d) * S8 + pos] = (ushort)s;
    } else {
        int o = atomicAdd(ovfc, 1);
        ovf[o] = ((uint)d << 16) | (uint)s;
    }
}

// ---------------- merge regions -> dense per-node list (fast gather layout) ----------
__global__ void k_merge(const int* __restrict__ cnt8, const ushort* __restrict__ slots8,
                        ushort* __restrict__ dense, int* __restrict__ deg_tot,
                        int* __restrict__ dcnt, uint* __restrict__ ovf,
                        int* __restrict__ ovfc) {
    int v = blockIdx.x * blockDim.x + threadIdx.x;
    if (v >= NN) return;
    int dg = 0, pos = 0;
    ushort* dst = dense + (size_t)v * DENSE;
#pragma unroll
    for (int r = 0; r < 8; r++) {
        int c = cnt8[r * NN + v];
        dg += c;
        int cc = c < S8 ? c : S8;
        const ushort* src = slots8 + ((size_t)r * NN + v) * S8;
        for (int j = 0; j < cc; j++) {
            ushort s = src[j];
            if (pos < DENSE) {
                dst[pos] = s;
            } else {
                int o = atomicAdd(ovfc, 1);
                ovf[o] = ((uint)v << 16) | (uint)s;
            }
            pos++;
        }
    }
    deg_tot[v] = dg;
    dcnt[v] = pos < DENSE ? pos : DENSE;
}

// ---------------- preprocessing kernel 0: B1 + c3 + h2b ----------------
__global__ void k_pre0(const float* __restrict__ W_ih, const float* __restrict__ W_msg,
                       const float* __restrict__ b_msg, const float* __restrict__ h,
                       float* __restrict__ B1, float* __restrict__ c3,
                       ushort* __restrict__ hb) {
    int b = blockIdx.x;
    int tid = threadIdx.x;
    if (b < 768) {
        int idx = b * 256 + tid;
        int k = idx % K2;
        int n = (idx / K2) % G3;
        int t = idx / (K2 * G3);
        const float* wi = W_ih + ((size_t)t * G3 + n) * K2;
        const float* wm = W_msg + (size_t)t * K2 * K2;
        float acc = 0.f;
#pragma unroll 8
        for (int j = 0; j < K2; j++) acc += wi[j] * wm[(size_t)j * K2 + k];
        B1[((size_t)t * K2 + k) * G3 + n] = acc;
    } else if (b < 771) {
        int idx = (b - 768) * 256 + tid;
        if (idx >= 2 * G3) return;
        int n = idx % G3;
        int t = idx / G3;
        const float* wi = W_ih + ((size_t)t * G3 + n) * K2;
        const float* bm = b_msg + t * K2;
        float acc = 0.f;
#pragma unroll 8
        for (int j = 0; j < K2; j++) acc += wi[j] * bm[j];
        c3[idx] = acc;
    } else {
        int i = (b - 771) * 256 + tid;
        if (i >= NN * HD / 4) return;
        float4 v = reinterpret_cast<const float4*>(h)[i];
        ushort4 o;
        o.x = f2b(v.x); o.y = f2b(v.y); o.z = f2b(v.z); o.w = f2b(v.w);
        reinterpret_cast<ushort4*>(hb)[i] = o;
    }
}

// ---------------- preprocessing kernel 1: pack B + biases ----------------
__global__ void k_pre1(const float* __restrict__ B1, const float* __restrict__ W_hh,
                       const float* __restrict__ b_ih, const float* __restrict__ b_hh,
                       const float* __restrict__ c3, ushort* __restrict__ Bq,
                       float* __restrict__ bih_p, float* __restrict__ bhh_p,
                       float* __restrict__ c3_p) {
    int b = blockIdx.x;
    int tid = threadIdx.x;
    if (b < 192) {
        int idx = b * 256 + tid;
        int lane = idx & 63;
        int slot = (idx >> 6) % 48;
        int slice = ((idx >> 6) / 48) % 8;
        int t = idx / (64 * 48 * 8);
        int slab = slot / 12;
        int rem = slot % 12;
        int kb = rem / 3, gate = rem % 3;
        int d = slice * 16 + (lane & 15);
        int kbase = kb * 32 + (lane >> 4) * 8;
        ushort* dst = Bq + (size_t)idx * 8;
#pragma unroll
        for (int e = 0; e < 8; e++) {
            int k = kbase + e;
            float v;
            if (slab == 0) {
                v = B1[((size_t)t * K2 + k) * G3 + gate * 128 + d];
            } else if (slab == 3) {
                v = W_hh[((size_t)t * G3 + gate * 128 + d) * HD + k];
            } else {
                float full = B1[((size_t)t * K2 + 128 + k) * G3 + gate * 128 + d];
                v = (slab == 1) ? full : (full - b2f(f2b(full)));
            }
            dst[e] = f2b(v);
        }
    } else {
        int idx = (b - 192) * 256 + tid;
        if (idx >= 2 * 8 * 3 * 16) return;
        int c = idx & 15;
        int g = (idx >> 4) % 3;
        int slice = ((idx >> 4) / 3) % 8;
        int t = idx / (16 * 3 * 8);
        int d = slice * 16 + c;
        bih_p[idx] = b_ih[t * G3 + g * 128 + d];
        bhh_p[idx] = b_hh[t * G3 + g * 128 + d];
        c3_p[idx]  = c3[t * G3 + g * 128 + d];
    }
}

// ---------------- prep: dense gather + write A [s|dh_hi|dh_lo|h_hi] frag order ------
__global__ void k_prep(const ushort* __restrict__ hb, const float* __restrict__ hf,
                       const int* __restrict__ deg_tot, const int* __restrict__ dcnt,
                       const ushort* __restrict__ dense,
                       const uint* __restrict__ ovf, const int* __restrict__ ovfc,
                       ushort* __restrict__ FA) {
    int wv = (blockIdx.x * blockDim.x + threadIdx.x) >> 6;
    int lane = threadIdx.x & 63;
    if (wv >= NN) return;
    int dg = deg_tot[wv];
    int lim = dcnt[wv];
    const ushort* sl = dense + (size_t)wv * DENSE;
    float a0 = 0.f, a1 = 0.f;
    int j = 0;
    for (; j + 16 <= lim; j += 16) {
        uint v[16];
#pragma unroll
        for (int q = 0; q < 16; q++) {
            int s = sl[j + q];
            v[q] = *reinterpret_cast<const uint*>(hb + (size_t)s * HD + lane * 2);
        }
#pragma unroll
        for (int q = 0; q < 16; q++) {
            a0 += b2f((ushort)(v[q] & 0xffff));
            a1 += b2f((ushort)(v[q] >> 16));
        }
    }
    for (; j + 4 <= lim; j += 4) {
        uint v[4];
#pragma unroll
        for (int q = 0; q < 4; q++) {
            int s = sl[j + q];
            v[q] = *reinterpret_cast<const uint*>(hb + (size_t)s * HD + lane * 2);
        }
#pragma unroll
        for (int q = 0; q < 4; q++) {
            a0 += b2f((ushort)(v[q] & 0xffff));
            a1 += b2f((ushort)(v[q] >> 16));
        }
    }
    for (; j < lim; j++) {
        int s = sl[j];
        uint v = *reinterpret_cast<const uint*>(hb + (size_t)s * HD + lane * 2);
        a0 += b2f((ushort)(v & 0xffff));
        a1 += b2f((ushort)(v >> 16));
    }
    if (dg > lim) {
        int oc = *ovfc;
        for (int k = 0; k < oc; k++) {
            uint pr = ovf[k];
            if ((int)(pr >> 16) == wv) {
                int s = (int)(pr & 0xffffu);
                uint v = *reinterpret_cast<const uint*>(hb + (size_t)s * HD + lane * 2);
                a0 += b2f((ushort)(v & 0xffff));
                a1 += b2f((ushort)(v >> 16));
            }
        }
    }
    int tile = wv >> 4, r = wv & 15;
    int kb = lane >> 4;
    int lp = r + (((lane & 15) >> 2) << 4);
    uint* base = reinterpret_cast<uint*>(FA) + (size_t)tile * 4096 + kb * 256 +
                 lp * 4 + (lane & 3);
    float2 hv = *reinterpret_cast<const float2*>(hf + (size_t)wv * HD + lane * 2);
    float dgf = (float)dg;
    float dh0 = dgf * hv.x, dh1 = dgf * hv.y;
    ushort p0 = f2b(dh0), p1 = f2b(dh1);
    ushort l0 = f2b(dh0 - b2f(p0)), l1 = f2b(dh1 - b2f(p1));
    base[0]    = pk(f2b(a0), f2b(a1));        // slab 0: s
    base[1024] = pk(p0, p1);                  // slab 1: dh_hi
    base[2048] = pk(l0, l1);                  // slab 2: dh_lo
    base[3072] = pk(f2b(hv.x), f2b(hv.y));    // slab 3: h_hi
}

// ---------------- fused MFMA GEMM + GRU: 8-wave octet blocks (round-14 proven) -------
#define BS(slab, kb, nf) \
    (*reinterpret_cast<const s16x8*>(&Bs[(size_t)((((slab) * 12 + (kb) * 3 + (nf)) * 64 + lane)) * 8]))

__global__ __launch_bounds__(512) void k_fused(
    const ushort* __restrict__ FA,      // [3125][16][64][8] bf16 frag-order A
    const ushort* __restrict__ Bq_t,    // [8][48][512] bf16 (this t)
    const float* __restrict__ bih_t,    // [8][3][16]
    const float* __restrict__ bhh_t,
    const float* __restrict__ c3_t,
    const int* __restrict__ deg,
    const float* __restrict__ hcur,     // [NN][128] f32
    float* __restrict__ hout,           // [NN][128] f32
    ushort* __restrict__ hb_out)        // [NN][128] bf16
{
    __shared__ __align__(16) ushort Bs[48 * 512];

    int tid = threadIdx.x;
    int bid = blockIdx.x;
    int r8 = bid & 7;
    int q = bid >> 3;
    int oct = (q >> 3) * 8 + r8;    // 0..103 ; valid < 98
    int slice = q & 7;
    if (oct * 32 >= NTILES) return; // whole block exits (uniform)
    int w = tid >> 6;               // 0..7
    int lane = tid & 63;
    int lhi = lane >> 4;
    int col = lane & 15;

    // stage B slice: 48 segs of 1KB; wave w loads 6
    const ushort* Bg = Bq_t + (size_t)slice * 48 * 512;
#pragma unroll
    for (int i = 0; i < 6; i++) {
        int seg = w * 6 + i;
        gl_lds16(Bg + (size_t)seg * 512 + lane * 8, &Bs[(size_t)seg * 512]);
    }

    int d = (slice << 4) + col;
    float bihv[3], bhhv[3], c3v[3];
#pragma unroll
    for (int g = 0; g < 3; g++) {
        int o = (slice * 3 + g) * 16 + col;
        bihv[g] = bih_t[o];
        bhhv[g] = bhh_t[o];
        c3v[g] = c3_t[o];
    }

    __syncthreads();   // single barrier: B resident (drains vmcnt)

#pragma unroll
    for (int it = 0; it < 4; it++) {
        int t = oct * 32 + w + 8 * it;   // wave-uniform
        if (t >= NTILES) break;
        const ushort* FAt = FA + (size_t)t * 8192;

        s16x8 As[4], Ahh[4], Ahl[4], Ah[4];
#pragma unroll
        for (int kb = 0; kb < 4; kb++) {
            As[kb]  = *reinterpret_cast<const s16x8*>(FAt + ((size_t)(kb) * 64 + lane) * 8);
            Ahh[kb] = *reinterpret_cast<const s16x8*>(FAt + ((size_t)(4 + kb) * 64 + lane) * 8);
            Ahl[kb] = *reinterpret_cast<const s16x8*>(FAt + ((size_t)(8 + kb) * 64 + lane) * 8);
            Ah[kb]  = *reinterpret_cast<const s16x8*>(FAt + ((size_t)(12 + kb) * 64 + lane) * 8);
        }

        int rbase0 = t * 16 + (lhi << 2);
        float hv[4];
        int dgi[4];
#pragma unroll
        for (int r = 0; r < 4; r++) {
            int m = rbase0 + r;
            int mm = m < NN ? m : 0;
            hv[r] = hcur[(size_t)mm * HD + d];
            dgi[r] = deg[mm];
        }

        f32x4 accI[3], accH[3];
#pragma unroll
        for (int i = 0; i < 3; i++) {
            accI[i] = f32x4{0.f, 0.f, 0.f, 0.f};
            accH[i] = f32x4{0.f, 0.f, 0.f, 0.f};
        }

#pragma unroll
        for (int kb = 0; kb < 4; kb++) {
#pragma unroll
            for (int nf = 0; nf < 3; nf++) {
                s16x8 b0 = BS(0, kb, nf);
                accI[nf] = __builtin_amdgcn_mfma_f32_16x16x32_bf16(As[kb], b0, accI[nf], 0, 0, 0);
                s16x8 b1 = BS(1, kb, nf);
                accI[nf] = __builtin_amdgcn_mfma_f32_16x16x32_bf16(Ahh[kb], b1, accI[nf], 0, 0, 0);
                accI[nf] = __builtin_amdgcn_mfma_f32_16x16x32_bf16(Ahl[kb], b1, accI[nf], 0, 0, 0);
                s16x8 b2 = BS(2, kb, nf);
                accI[nf] = __builtin_amdgcn_mfma_f32_16x16x32_bf16(Ahh[kb], b2, accI[nf], 0, 0, 0);
                s16x8 b3 = BS(3, kb, nf);
                accH[nf] = __builtin_amdgcn_mfma_f32_16x16x32_bf16(Ah[kb], b3, accH[nf], 0, 0, 0);
            }
        }

#pragma unroll
        for (int r = 0; r < 4; r++) {
            int m = rbase0 + r;
            bool wr = m < NN;
            float dgf = (float)dgi[r];
            float ir  = accI[0][r] + dgf * c3v[0] + bihv[0];
            float iz  = accI[1][r] + dgf * c3v[1] + bihv[1];
            float in_ = accI[2][r] + dgf * c3v[2] + bihv[2];
            float hr = accH[0][r] + bhhv[0];
            float hz = accH[1][r] + bhhv[1];
            float hn = accH[2][r] + bhhv[2];
            float rg = fsig(ir + hr);
            float zg = fsig(iz + hz);
            float ng = ftanh(in_ + rg * hn);
            float hnew = (1.f - zg) * ng + zg * hv[r];
            float res = (dgi[r] > 0) ? hnew : hv[r];
            if (wr) {
                hout[(size_t)m * HD + d] = res;
                hb_out[(size_t)m * HD + d] = f2b(res);
            }
        }
    }
}

extern "C" void kernel_launch(void* const* d_in, const int* in_sizes, int n_in,
                              void* d_out, int out_size, void* d_ws, size_t ws_size,
                              hipStream_t stream) {
    const float* h_in  = (const float*)d_in[0];
    const int*   edges = (const int*)d_in[1];
    const float* W_msg = (const float*)d_in[2];
    const float* b_msg = (const float*)d_in[3];
    const float* W_ih  = (const float*)d_in[4];
    const float* W_hh  = (const float*)d_in[5];
    const float* b_ih  = (const float*)d_in[6];
    const float* b_hh  = (const float*)d_in[7];
    float* out = (float*)d_out;

    char* p = (char*)d_ws;
    auto alloc = [&](size_t bytes) {
        void* r = (void*)p;
        p += (bytes + 255) / 256 * 256;
        return r;
    };
    int*    cnt8    = (int*)alloc((size_t)(8 * NN + 1) * 4);  // +1: ovf counter
    ushort* slots8  = (ushort*)alloc((size_t)8 * NN * S8 * 2);
    ushort* dense   = (ushort*)alloc((size_t)NN * DENSE * 2);
    uint*   ovf     = (uint*)alloc((size_t)NE * 4);
    int*    deg_tot = (int*)alloc((size_t)NN * 4);
    int*    dcnt    = (int*)alloc((size_t)NN * 4);
    float*  B1      = (float*)alloc((size_t)2 * K2 * G3 * 4);
    float*  c3      = (float*)alloc((size_t)2 * G3 * 4);
    ushort* Bq      = (ushort*)alloc((size_t)2 * 8 * 48 * 512 * 2);
    float*  bih_p   = (float*)alloc((size_t)2 * 8 * 3 * 16 * 4);
    float*  bhh_p   = (float*)alloc((size_t)2 * 8 * 3 * 16 * 4);
    float*  c3_p    = (float*)alloc((size_t)2 * 8 * 3 * 16 * 4);
    ushort* hb0     = (ushort*)alloc((size_t)NN * HD * 2);
    ushort* hb1     = (ushort*)alloc((size_t)NN * HD * 2);
    ushort* FA      = (ushort*)alloc((size_t)NTILES * 8192 * 2);
    float*  h1      = (float*)alloc((size_t)NN * HD * 4);
    int*    ovfc    = cnt8 + 8 * NN;

    hipMemsetAsync(cnt8, 0, (size_t)(8 * NN + 1) * 4, stream);
    k_fill1<<<(NE + 255) / 256, 256, 0, stream>>>(edges, cnt8, slots8, ovf, ovfc);
    k_merge<<<(NN + 255) / 256, 256, 0, stream>>>(cnt8, slots8, dense, deg_tot, dcnt,
                                                  ovf, ovfc);
    k_pre0<<<771 + (NN * HD / 4 + 255) / 256, 256, 0, stream>>>(
        W_ih, W_msg, b_msg, h_in, B1, c3, hb0);
    k_pre1<<<195, 256, 0, stream>>>(B1, W_hh, b_ih, b_hh, c3, Bq, bih_p, bhh_p, c3_p);

    const int FGRID = 832;
    const size_t BqT = (size_t)8 * 48 * 512;   // ushort units per t
    const size_t biasT = (size_t)8 * 3 * 16;

    // step 0
    k_prep<<<(NN * 64 + 255) / 256, 256, 0, stream>>>(hb0, h_in, deg_tot, dcnt, dense,
                                                      ovf, ovfc, FA);
    k_fused<<<FGRID, 512, 0, stream>>>(FA, Bq, bih_p, bhh_p, c3_p, deg_tot, h_in, h1, hb1);
    // step 1 (hb0 is rebuilt by k_pre0 every launch)
    k_prep<<<(NN * 64 + 255) / 256, 256, 0, stream>>>(hb1, h1, deg_tot, dcnt, dense,
                                                      ovf, ovfc, FA);
    k_fused<<<FGRID, 512, 0, stream>>>(FA, Bq + BqT, bih_p + biasT, bhh_p + biasT,
                                       c3_p + biasT, deg_tot, h1, out, hb0);
}